// Round 5
// baseline (634.653 us; speedup 1.0000x reference)
//
#include <hip/hip_runtime.h>
#include <hip/hip_cooperative_groups.h>

namespace cg = cooperative_groups;

#define IH 126
#define IW 126
#define HW 15876      // 126*126
#define OH 124
#define OW 124
#define OHW 15376     // 124*124

// ---------------------------------------------------------------- conv_in
__global__ __launch_bounds__(256) void conv_in_kernel(
    const float* __restrict__ x, const float* __restrict__ w,
    const float* __restrict__ b, float* __restrict__ y)
{
  int pix = blockIdx.x * 256 + threadIdx.x;
  if (pix >= HW) return;
  int oc = blockIdx.y;                 // wave-uniform -> weights become s_loads
  int h  = pix / IW;
  int wc = pix - h * IW;
  const float* wp = w + oc * 27;
  float acc = b[oc];
#pragma unroll
  for (int ci = 0; ci < 3; ci++)
#pragma unroll
    for (int ky = 0; ky < 3; ky++)
#pragma unroll
      for (int kx = 0; kx < 3; kx++)
        acc = fmaf(x[ci * 128 * 128 + (h + ky) * 128 + (wc + kx)],
                   wp[ci * 9 + ky * 3 + kx], acc);
  y[oc * HW + pix] = acc;
}

#define XSW(c, pos) ((c) ^ (((pos) & 7) << 3))
#define WVP 36

// ---------------------------------------------------------------- inv_all (v8)
// ALL 6 involution layers in ONE cooperative dispatch: 512 blocks x 512 thr,
// LDS 81,408 B -> exactly 2 blocks/CU = 512 co-resident (cooperative req.).
// grid.sync() between layers replaces 5 kernel launches.
// Per layer = v7 structure + span-weights staged in LDS during phase A
// (kills the 25 dependent wave-uniform s_load chains in phase C).
__global__ __launch_bounds__(512, 4) void inv_all_kernel(
    float* __restrict__ bufA, float* __restrict__ bufB,
    const float* __restrict__ wr0, const float* __restrict__ br0,
    const float* __restrict__ gam0, const float* __restrict__ bet0,
    const float* __restrict__ mu0, const float* __restrict__ var0,
    const float* __restrict__ wspan0, const float* __restrict__ bspan0)
{
  __shared__ __align__(16) float xs[140][68];   // 38,080 B; aliased by ob[64][33]
  __shared__ __align__(16) float wvs[196 * WVP];// 28,224 B
  __shared__ __align__(16) float tss[640];      // 2,560 B; [32 px][20]
  __shared__ __align__(16) float wsm[3136];     // 12,544 B; staged span weights
  float* ob = &xs[0][0];                        // [64][33] alias

  cg::grid_group grid = cg::this_grid();

  int tid = threadIdx.x;
  int bx = blockIdx.x & 15, by = blockIdx.x >> 4;
  int ox0 = bx * 8, oy0 = by * 4;
  int xh0 = ox0 - 3, yh0 = oy0 - 3;
  int w_ = __builtin_amdgcn_readfirstlane(tid >> 6);  // wave 0..7
  int ln = tid & 63;
  int p  = ln & 31;                   // pixel 0..31 (upper 32 lanes duplicate)
  int prow = p >> 3, pcol = p & 7;
  int pc = (prow + 3) * 14 + (pcol + 3);

  for (int layer = 0; layer < 6; layer++) {
    if (layer > 0) grid.sync();       // all blocks' layer-(L-1) writes visible

    const float* x     = (layer & 1) ? bufB : bufA;
    float*       y     = (layer & 1) ? bufA : bufB;
    const float* wr    = wr0    + layer * 16 * 64;
    const float* br    = br0    + layer * 16;
    const float* gam   = gam0   + layer * 16;
    const float* bet   = bet0   + layer * 16;
    const float* mu    = mu0    + layer * 16;
    const float* var   = var0   + layer * 16;
    const float* wspan = wspan0 + layer * 196 * 16;
    const float* bspan = bspan0 + layer * 196;

    // ---- Phase A: stage x halo (14 x 10 x 64 ch) + span weights into LDS
    for (int idx = tid; idx < 140 * 64; idx += 512) {
      int c = idx / 140;
      int pos = idx - c * 140;
      int row = pos / 14;
      int col = pos - row * 14;
      int gy = yh0 + row, gx = xh0 + col;
      float v = 0.f;
      if (gy >= 0 && gy < IH && gx >= 0 && gx < IW)
        v = x[c * HW + gy * IW + gx];
      xs[pos][XSW(c, pos)] = v;
    }
    for (int j = tid; j < 3136; j += 512) wsm[j] = wspan[j];
    __syncthreads();

    // ---- Phase B: t = ReLU(BN(Wr.x)); wave w_ does cr = 2w_, 2w_+1
    {
      int cr0 = 2 * w_;
      const float* wa = wr + cr0 * 64;  // uniform -> s_load
      const float* wb = wa + 64;
      float a0 = 0.f, a1 = 0.f;
      int xsw = (pc & 7) << 3;
#pragma unroll
      for (int ci = 0; ci < 64; ci += 4) {
        int cis = ci ^ xsw;
        float4 xv = *(const float4*)&xs[pc][cis];
        a0 = fmaf(xv.x, wa[cis + 0], a0); a1 = fmaf(xv.x, wb[cis + 0], a1);
        a0 = fmaf(xv.y, wa[cis + 1], a0); a1 = fmaf(xv.y, wb[cis + 1], a1);
        a0 = fmaf(xv.z, wa[cis + 2], a0); a1 = fmaf(xv.z, wb[cis + 2], a1);
        a0 = fmaf(xv.w, wa[cis + 3], a0); a1 = fmaf(xv.w, wb[cis + 3], a1);
      }
      float s0 = gam[cr0]     * rsqrtf(var[cr0]     + 1e-5f);
      float s1 = gam[cr0 + 1] * rsqrtf(var[cr0 + 1] + 1e-5f);
      float t0 = (a0 + br[cr0]     - mu[cr0])     * s0 + bet[cr0];
      float t1 = (a1 + br[cr0 + 1] - mu[cr0 + 1]) * s1 + bet[cr0 + 1];
      if (ln < 32) {
        tss[p * 20 + cr0]     = fmaxf(t0, 0.f);
        tss[p * 20 + cr0 + 1] = fmaxf(t1, 0.f);
      }
    }
    __syncthreads();

    // ---- Phase C: span from LDS weights (broadcast ds_reads, no s_load chain)
    {
      float tv[16];
#pragma unroll
      for (int i = 0; i < 4; i++) {
        float4 t4 = *(const float4*)&tss[p * 20 + 4 * i];
        tv[4 * i] = t4.x; tv[4 * i + 1] = t4.y;
        tv[4 * i + 2] = t4.z; tv[4 * i + 3] = t4.w;
      }
      for (int j = 0; j < 25; j++) {
        int pair = w_ + 8 * j;           // wave-uniform
        if (pair < 196) {
          const float* wk = &wsm[pair * 16];   // uniform LDS -> broadcast
          float a = bspan[pair];
#pragma unroll
          for (int i = 0; i < 16; i++) a = fmaf(tv[i], wk[i], a);
          if (ln < 32) wvs[pair * WVP + pcol * 4 + prow] = a;
        }
      }
    }
    __syncthreads();

    // ---- Phase D: einsum. wave = output column w_, lane = channel.
    float acc0 = 0.f, acc1 = 0.f, acc2 = 0.f, acc3 = 0.f;
    {
      int c = ln;
      int g = ln >> 4;
      float xw[4][7];
#pragma unroll
      for (int r = 0; r < 4; r++)
#pragma unroll
        for (int kx = 0; kx < 7; kx++) {
          int pos = r * 14 + w_ + kx;
          xw[r][kx] = xs[pos][XSW(c, pos)];
        }
#pragma unroll
      for (int ky = 0; ky < 7; ky++) {
        if (ky > 0) {
#pragma unroll
          for (int r = 0; r < 3; r++)
#pragma unroll
            for (int kx = 0; kx < 7; kx++) xw[r][kx] = xw[r + 1][kx];
#pragma unroll
          for (int kx = 0; kx < 7; kx++) {
            int pos = (ky + 3) * 14 + w_ + kx;
            xw[3][kx] = xs[pos][XSW(c, pos)];
          }
        }
#pragma unroll
        for (int kx = 0; kx < 7; kx++) {
          int k = ky * 7 + kx;
          float4 w4 = *(const float4*)&wvs[(g * 49 + k) * WVP + w_ * 4];
          acc0 = fmaf(w4.x, xw[0][kx], acc0);
          acc1 = fmaf(w4.y, xw[1][kx], acc1);
          acc2 = fmaf(w4.z, xw[2][kx], acc2);
          acc3 = fmaf(w4.w, xw[3][kx], acc3);
        }
      }
    }
    __syncthreads();                   // xs reads done; safe to alias with ob

    // ---- Phase E: transpose via LDS, coalesced store (+outer ReLU)
    {
      int c = ln;
      ob[c * 33 + 0 * 8 + w_] = fmaxf(acc0, 0.f);
      ob[c * 33 + 1 * 8 + w_] = fmaxf(acc1, 0.f);
      ob[c * 33 + 2 * 8 + w_] = fmaxf(acc2, 0.f);
      ob[c * 33 + 3 * 8 + w_] = fmaxf(acc3, 0.f);
    }
    __syncthreads();
    for (int j = tid; j < 2048; j += 512) {
      int c2 = j >> 5, pp = j & 31;
      int pr = pp >> 3, pc2 = pp & 7;
      int gy = oy0 + pr, gx = ox0 + pc2;
      if (gy < IH && gx < IW)
        y[c2 * HW + gy * IW + gx] = ob[c2 * 33 + pp];
    }
  }
}

// ---------------------------------------------------------------- inv fallback (v7, single layer)
__global__ __launch_bounds__(512, 4) void inv_kernel(
    const float* __restrict__ x, float* __restrict__ y,
    const float* __restrict__ wr, const float* __restrict__ br,
    const float* __restrict__ gam, const float* __restrict__ bet,
    const float* __restrict__ mu, const float* __restrict__ var,
    const float* __restrict__ wspan, const float* __restrict__ bspan)
{
  __shared__ __align__(16) float xs[140][68];
  __shared__ __align__(16) float wvs[196 * WVP];
  __shared__ __align__(16) float tss[640];
  float* ob  = &xs[0][0];

  int tid = threadIdx.x;
  int bx = blockIdx.x & 15, by = blockIdx.x >> 4;
  int ox0 = bx * 8, oy0 = by * 4;
  int xh0 = ox0 - 3, yh0 = oy0 - 3;

  for (int idx = tid; idx < 140 * 64; idx += 512) {
    int c = idx / 140;
    int pos = idx - c * 140;
    int row = pos / 14;
    int col = pos - row * 14;
    int gy = yh0 + row, gx = xh0 + col;
    float v = 0.f;
    if (gy >= 0 && gy < IH && gx >= 0 && gx < IW)
      v = x[c * HW + gy * IW + gx];
    xs[pos][XSW(c, pos)] = v;
  }
  __syncthreads();

  int w_ = __builtin_amdgcn_readfirstlane(tid >> 6);
  int ln = tid & 63;
  int p  = ln & 31;
  int prow = p >> 3, pcol = p & 7;
  int pc = (prow + 3) * 14 + (pcol + 3);

  {
    int cr0 = 2 * w_;
    const float* wa = wr + cr0 * 64;
    const float* wb = wa + 64;
    float a0 = 0.f, a1 = 0.f;
    int xsw = (pc & 7) << 3;
#pragma unroll
    for (int ci = 0; ci < 64; ci += 4) {
      int cis = ci ^ xsw;
      float4 xv = *(const float4*)&xs[pc][cis];
      a0 = fmaf(xv.x, wa[cis + 0], a0); a1 = fmaf(xv.x, wb[cis + 0], a1);
      a0 = fmaf(xv.y, wa[cis + 1], a0); a1 = fmaf(xv.y, wb[cis + 1], a1);
      a0 = fmaf(xv.z, wa[cis + 2], a0); a1 = fmaf(xv.z, wb[cis + 2], a1);
      a0 = fmaf(xv.w, wa[cis + 3], a0); a1 = fmaf(xv.w, wb[cis + 3], a1);
    }
    float s0 = gam[cr0]     * rsqrtf(var[cr0]     + 1e-5f);
    float s1 = gam[cr0 + 1] * rsqrtf(var[cr0 + 1] + 1e-5f);
    float t0 = (a0 + br[cr0]     - mu[cr0])     * s0 + bet[cr0];
    float t1 = (a1 + br[cr0 + 1] - mu[cr0 + 1]) * s1 + bet[cr0 + 1];
    if (ln < 32) {
      tss[p * 20 + cr0]     = fmaxf(t0, 0.f);
      tss[p * 20 + cr0 + 1] = fmaxf(t1, 0.f);
    }
  }
  __syncthreads();

  {
    float tv[16];
#pragma unroll
    for (int i = 0; i < 4; i++) {
      float4 t4 = *(const float4*)&tss[p * 20 + 4 * i];
      tv[4 * i] = t4.x; tv[4 * i + 1] = t4.y;
      tv[4 * i + 2] = t4.z; tv[4 * i + 3] = t4.w;
    }
    for (int j = 0; j < 25; j++) {
      int pair = w_ + 8 * j;
      if (pair < 196) {
        const float* wk = wspan + pair * 16;
        float a = bspan[pair];
#pragma unroll
        for (int i = 0; i < 16; i++) a = fmaf(tv[i], wk[i], a);
        if (ln < 32) wvs[pair * WVP + pcol * 4 + prow] = a;
      }
    }
  }
  __syncthreads();

  float acc0 = 0.f, acc1 = 0.f, acc2 = 0.f, acc3 = 0.f;
  {
    int c = ln;
    int g = ln >> 4;
    float xw[4][7];
#pragma unroll
    for (int r = 0; r < 4; r++)
#pragma unroll
      for (int kx = 0; kx < 7; kx++) {
        int pos = r * 14 + w_ + kx;
        xw[r][kx] = xs[pos][XSW(c, pos)];
      }
#pragma unroll
    for (int ky = 0; ky < 7; ky++) {
      if (ky > 0) {
#pragma unroll
        for (int r = 0; r < 3; r++)
#pragma unroll
          for (int kx = 0; kx < 7; kx++) xw[r][kx] = xw[r + 1][kx];
#pragma unroll
        for (int kx = 0; kx < 7; kx++) {
          int pos = (ky + 3) * 14 + w_ + kx;
          xw[3][kx] = xs[pos][XSW(c, pos)];
        }
      }
#pragma unroll
      for (int kx = 0; kx < 7; kx++) {
        int k = ky * 7 + kx;
        float4 w4 = *(const float4*)&wvs[(g * 49 + k) * WVP + w_ * 4];
        acc0 = fmaf(w4.x, xw[0][kx], acc0);
        acc1 = fmaf(w4.y, xw[1][kx], acc1);
        acc2 = fmaf(w4.z, xw[2][kx], acc2);
        acc3 = fmaf(w4.w, xw[3][kx], acc3);
      }
    }
  }
  __syncthreads();

  {
    int c = ln;
    ob[c * 33 + 0 * 8 + w_] = fmaxf(acc0, 0.f);
    ob[c * 33 + 1 * 8 + w_] = fmaxf(acc1, 0.f);
    ob[c * 33 + 2 * 8 + w_] = fmaxf(acc2, 0.f);
    ob[c * 33 + 3 * 8 + w_] = fmaxf(acc3, 0.f);
  }
  __syncthreads();
  for (int j = tid; j < 2048; j += 512) {
    int c2 = j >> 5, pp = j & 31;
    int pr = pp >> 3, pc2 = pp & 7;
    int gy = oy0 + pr, gx = ox0 + pc2;
    if (gy < IH && gx < IW)
      y[c2 * HW + gy * IW + gx] = ob[c2 * 33 + pp];
  }
}

// ---------------------------------------------------------------- conv_out prep
__global__ __launch_bounds__(256) void transpose_w_kernel(
    const float* __restrict__ w, float* __restrict__ wt)
{
  int i = blockIdx.x * 256 + threadIdx.x;
  if (i >= 128 * 64 * 9) return;
  int oc = i / 576;
  int rem = i - oc * 576;
  int ci = rem / 9;
  int k = rem - ci * 9;
  wt[(k * 64 + ci) * 128 + oc] = w[i];
}

// ---------------------------------------------------------------- conv_out v3 (best measured)
__global__ __launch_bounds__(256, 6) void conv_out_kernel(
    const float* __restrict__ x, const float* __restrict__ wt,
    const float* __restrict__ b, float* __restrict__ y)
{
  __shared__ __align__(16) float xsm[16 * 100 * 4];   // 25,600 B
  int tid = threadIdx.x;
  int bx = blockIdx.x & 15, by = blockIdx.x >> 4;
  int oy0 = by * 8, ox0 = bx * 8;

  for (int u = tid; u < 1600; u += 256) {
    int cq = u / 100;
    int pos = u - cq * 100;
    int row = pos / 10;
    int col = pos - row * 10;
    int gy = oy0 + row, gx = ox0 + col;
    float4 v = make_float4(0.f, 0.f, 0.f, 0.f);
    if (gy < IH && gx < IW) {
      const float* xp = x + cq * 4 * HW + gy * IW + gx;
      v.x = xp[0]; v.y = xp[HW]; v.z = xp[2 * HW]; v.w = xp[3 * HW];
    }
    *(float4*)&xsm[u * 4] = v;
  }
  __syncthreads();

  int ln = tid & 63;
  int px = ln & 7, py = ln >> 3;
  int wv_ = __builtin_amdgcn_readfirstlane(tid >> 6);   // wave 0..3
  int oc8 = blockIdx.y * 32 + wv_ * 8;

  float acc[8];
#pragma unroll
  for (int j = 0; j < 8; j++) acc[j] = b[oc8 + j];

#pragma unroll
  for (int ky = 0; ky < 3; ky++) {
#pragma unroll
    for (int kx = 0; kx < 3; kx++) {
      int k = ky * 3 + kx;
      int pidx = (py + ky) * 10 + px + kx;
      const float* wp = wt + k * 64 * 128 + oc8;   // uniform -> s_loads
#pragma unroll 4
      for (int cq = 0; cq < 16; cq++) {
        float4 xv = *(const float4*)&xsm[(cq * 100 + pidx) * 4];
        const float* wq = wp + cq * 4 * 128;
#pragma unroll
        for (int j = 0; j < 8; j++) {
          acc[j] = fmaf(xv.x, wq[0 * 128 + j], acc[j]);
          acc[j] = fmaf(xv.y, wq[1 * 128 + j], acc[j]);
          acc[j] = fmaf(xv.z, wq[2 * 128 + j], acc[j]);
          acc[j] = fmaf(xv.w, wq[3 * 128 + j], acc[j]);
        }
      }
    }
  }

  int oy = oy0 + py, ox = ox0 + px;
  if (oy < OH && ox < OW) {
#pragma unroll
    for (int j = 0; j < 8; j++)
      y[(oc8 + j) * OHW + oy * OW + ox] = acc[j];
  }
}

// ---------------------------------------------------------------- launch
extern "C" void kernel_launch(void* const* d_in, const int* in_sizes, int n_in,
                              void* d_out, int out_size, void* d_ws, size_t ws_size,
                              hipStream_t stream)
{
  const float* input = (const float*)d_in[0];
  const float* ciw   = (const float*)d_in[1];
  const float* cib   = (const float*)d_in[2];
  const float* wred  = (const float*)d_in[3];
  const float* bred  = (const float*)d_in[4];
  const float* gam   = (const float*)d_in[5];
  const float* bet   = (const float*)d_in[6];
  const float* mu    = (const float*)d_in[7];
  const float* var   = (const float*)d_in[8];
  const float* wspan = (const float*)d_in[9];
  const float* bspan = (const float*)d_in[10];
  const float* cow   = (const float*)d_in[11];
  const float* cob   = (const float*)d_in[12];
  float* out = (float*)d_out;

  float* bufA = (float*)d_ws;                 // 64*126*126 = 1,016,064 floats
  float* bufB = bufA + (1 << 20);             // @ 4 MiB
  float* wt   = bufA + (1 << 21);             // @ 8 MiB, 73,728 floats

  transpose_w_kernel<<<288, 256, 0, stream>>>(cow, wt);
  conv_in_kernel<<<dim3(63, 64), 256, 0, stream>>>(input, ciw, cib, bufA);

  // all 6 involution layers in one cooperative dispatch (512 blocks = exactly
  // 2/CU x 256 CU co-resident). Falls back to 6 separate launches on error.
  {
    void* args[] = {&bufA, &bufB, (void*)&wred, (void*)&bred, (void*)&gam,
                    (void*)&bet, (void*)&mu, (void*)&var, (void*)&wspan,
                    (void*)&bspan};
    hipError_t e = hipLaunchCooperativeKernel(
        reinterpret_cast<void*>(inv_all_kernel), dim3(512), dim3(512),
        args, 0, stream);
    if (e != hipSuccess) {
      float* cur = bufA; float* nxt = bufB;
      for (int i = 0; i < 6; i++) {
        inv_kernel<<<512, 512, 0, stream>>>(cur, nxt,
            wred + i * 16 * 64, bred + i * 16, gam + i * 16, bet + i * 16,
            mu + i * 16, var + i * 16, wspan + i * 196 * 16, bspan + i * 196);
        float* t = cur; cur = nxt; nxt = t;
      }
    }
  }

  conv_out_kernel<<<dim3(256, 4), 256, 0, stream>>>(bufA, wt, cob, out);
}

// Round 6
// 238.096 us; speedup vs baseline: 2.6655x; 2.6655x over previous
//
#include <hip/hip_runtime.h>

#define IH 126
#define IW 126
#define HW 15876      // 126*126
#define OH 124
#define OW 124
#define OHW 15376     // 124*124

// Activations between kernels are stored HWC (channels-last): a[(y*IW+x)*64 + c].
// Every producer/consumer then touches 256 B contiguous per pixel -> HBM sector
// amplification ~1.0 (was ~5x write / ~2.3x read in CHW; r5 counters).

// ---------------------------------------------------------------- conv_in (HWC out)
// wave = pixel (uniform x taps -> s_loads), lane = oc. 256 B contiguous stores.
__global__ __launch_bounds__(256) void conv_in_kernel(
    const float* __restrict__ x, const float* __restrict__ w,
    const float* __restrict__ b, float* __restrict__ y)
{
  int tid = threadIdx.x;
  int oc = tid & 63;
  int w_ = __builtin_amdgcn_readfirstlane(tid >> 6);   // wave 0..3
  int pix = blockIdx.x * 4 + w_;
  if (pix >= HW) return;
  int h  = pix / IW;
  int wc = pix - h * IW;
  const float* wp = w + oc * 27;       // lane-strided, L1-hot after warmup
  float acc = b[oc];
#pragma unroll
  for (int ci = 0; ci < 3; ci++)
#pragma unroll
    for (int ky = 0; ky < 3; ky++)
#pragma unroll
      for (int kx = 0; kx < 3; kx++)
        acc = fmaf(x[ci * 128 * 128 + (h + ky) * 128 + (wc + kx)],   // uniform
                   wp[ci * 9 + ky * 3 + kx], acc);
  y[pix * 64 + oc] = acc;
}

#define XSW(c, pos) ((c) ^ (((pos) & 7) << 3))
#define WVP 36

// ---------------------------------------------------------------- involution v9
// r4 structure (passed) with HWC activations:
//   Phase A: float4-over-channels staging (4.4 VMEM inst/thread, 256 B runs).
//   Phase E: GONE — phase D stores directly, 256 B contiguous per (pixel).
//   Phases B/C/D identical to r4. LDS 68,864 B -> 2 blocks/CU.
__global__ __launch_bounds__(512, 4) void inv_kernel(
    const float* __restrict__ x, float* __restrict__ y,
    const float* __restrict__ wr, const float* __restrict__ br,
    const float* __restrict__ gam, const float* __restrict__ bet,
    const float* __restrict__ mu, const float* __restrict__ var,
    const float* __restrict__ wspan, const float* __restrict__ bspan)
{
  __shared__ __align__(16) float xs[140][68];   // 38,080 B
  __shared__ __align__(16) float wvs[196 * WVP];// 28,224 B
  __shared__ __align__(16) float tss[640];      // 2,560 B; [32 px][20]

  int tid = threadIdx.x;
  int bx = blockIdx.x & 15, by = blockIdx.x >> 4;
  int ox0 = bx * 8, oy0 = by * 4;
  int xh0 = ox0 - 3, yh0 = oy0 - 3;

  // ---- Phase A: stage x halo (14 cols x 10 rows x 64 ch) from HWC, float4
  for (int idx = tid; idx < 140 * 16; idx += 512) {
    int pos = idx >> 4;
    int c4  = (idx & 15) << 2;
    int row = pos / 14;
    int col = pos - row * 14;
    int gy = yh0 + row, gx = xh0 + col;
    float4 v = make_float4(0.f, 0.f, 0.f, 0.f);
    if (gy >= 0 && gy < IH && gx >= 0 && gx < IW)
      v = *(const float4*)&x[(gy * IW + gx) * 64 + c4];
    *(float4*)&xs[pos][XSW(c4, pos)] = v;     // XSW preserves float4 alignment
  }
  __syncthreads();

  int w_ = __builtin_amdgcn_readfirstlane(tid >> 6);  // wave 0..7
  int ln = tid & 63;
  int p  = ln & 31;                   // pixel 0..31 (upper 32 lanes duplicate)
  int prow = p >> 3, pcol = p & 7;
  int pc = (prow + 3) * 14 + (pcol + 3);

  // ---- Phase B: t = ReLU(BN(Wr.x)); wave w_ does cr = 2w_, 2w_+1 (uniform)
  {
    int cr0 = 2 * w_;
    const float* wa = wr + cr0 * 64;  // uniform -> s_load
    const float* wb = wa + 64;
    float a0 = 0.f, a1 = 0.f;
    int xsw = (pc & 7) << 3;
#pragma unroll
    for (int ci = 0; ci < 64; ci += 4) {
      int cis = ci ^ xsw;
      float4 xv = *(const float4*)&xs[pc][cis];
      a0 = fmaf(xv.x, wa[cis + 0], a0); a1 = fmaf(xv.x, wb[cis + 0], a1);
      a0 = fmaf(xv.y, wa[cis + 1], a0); a1 = fmaf(xv.y, wb[cis + 1], a1);
      a0 = fmaf(xv.z, wa[cis + 2], a0); a1 = fmaf(xv.z, wb[cis + 2], a1);
      a0 = fmaf(xv.w, wa[cis + 3], a0); a1 = fmaf(xv.w, wb[cis + 3], a1);
    }
    float s0 = gam[cr0]     * rsqrtf(var[cr0]     + 1e-5f);
    float s1 = gam[cr0 + 1] * rsqrtf(var[cr0 + 1] + 1e-5f);
    float t0 = (a0 + br[cr0]     - mu[cr0])     * s0 + bet[cr0];
    float t1 = (a1 + br[cr0 + 1] - mu[cr0 + 1]) * s1 + bet[cr0 + 1];
    if (ln < 32) {
      tss[p * 20 + cr0]     = fmaxf(t0, 0.f);
      tss[p * 20 + cr0 + 1] = fmaxf(t1, 0.f);
    }
  }
  __syncthreads();

  // ---- Phase C: span. wave w_ owns uniform pairs (g*49+k) = w_ + 8j.
  {
    float tv[16];
#pragma unroll
    for (int i = 0; i < 4; i++) {
      float4 t4 = *(const float4*)&tss[p * 20 + 4 * i];
      tv[4 * i] = t4.x; tv[4 * i + 1] = t4.y;
      tv[4 * i + 2] = t4.z; tv[4 * i + 3] = t4.w;
    }
    for (int j = 0; j < 25; j++) {
      int pair = w_ + 8 * j;           // wave-uniform
      if (pair < 196) {
        const float* wk = wspan + pair * 16;   // uniform -> s_load_dwordx16
        float a = bspan[pair];
#pragma unroll
        for (int i = 0; i < 16; i++) a = fmaf(tv[i], wk[i], a);
        if (ln < 32) wvs[pair * WVP + pcol * 4 + prow] = a;
      }
    }
  }
  __syncthreads();

  // ---- Phase D: einsum. wave = output column w_, lane = channel.
  float acc0 = 0.f, acc1 = 0.f, acc2 = 0.f, acc3 = 0.f;
  {
    int c = ln;
    int g = ln >> 4;
    float xw[4][7];
#pragma unroll
    for (int r = 0; r < 4; r++)
#pragma unroll
      for (int kx = 0; kx < 7; kx++) {
        int pos = r * 14 + w_ + kx;            // wave-uniform base + lane
        xw[r][kx] = xs[pos][XSW(c, pos)];
      }
#pragma unroll
    for (int ky = 0; ky < 7; ky++) {
      if (ky > 0) {
#pragma unroll
        for (int r = 0; r < 3; r++)
#pragma unroll
          for (int kx = 0; kx < 7; kx++) xw[r][kx] = xw[r + 1][kx];
#pragma unroll
        for (int kx = 0; kx < 7; kx++) {
          int pos = (ky + 3) * 14 + w_ + kx;
          xw[3][kx] = xs[pos][XSW(c, pos)];
        }
      }
#pragma unroll
      for (int kx = 0; kx < 7; kx++) {
        int k = ky * 7 + kx;
        float4 w4 = *(const float4*)&wvs[(g * 49 + k) * WVP + w_ * 4];
        acc0 = fmaf(w4.x, xw[0][kx], acc0);
        acc1 = fmaf(w4.y, xw[1][kx], acc1);
        acc2 = fmaf(w4.z, xw[2][kx], acc2);
        acc3 = fmaf(w4.w, xw[3][kx], acc3);
      }
    }
  }

  // ---- store directly to HWC (outer ReLU fused): 256 B contiguous per pixel
  {
    int c = ln;
    int gx = ox0 + w_;
    if (gx < IW) {
      int base = (oy0 * IW + gx) * 64 + c;
      y[base]               = fmaxf(acc0, 0.f);      // oy0   <= 124: in range
      y[base + 1 * IW * 64] = fmaxf(acc1, 0.f);      // oy0+1 <= 125: in range
      if (oy0 + 2 < IH) y[base + 2 * IW * 64] = fmaxf(acc2, 0.f);
      if (oy0 + 3 < IH) y[base + 3 * IW * 64] = fmaxf(acc3, 0.f);
    }
  }
}

// ---------------------------------------------------------------- conv_out prep
__global__ __launch_bounds__(256) void transpose_w_kernel(
    const float* __restrict__ w, float* __restrict__ wt)
{
  int i = blockIdx.x * 256 + threadIdx.x;
  if (i >= 128 * 64 * 9) return;
  int oc = i / 576;
  int rem = i - oc * 576;
  int ci = rem / 9;
  int k = rem - ci * 9;
  wt[(k * 64 + ci) * 128 + oc] = w[i];
}

// ---------------------------------------------------------------- conv_out v3 (best measured)
// Only the staging loop changed: one float4 HWC load per (pos,cq) instead of
// 4 scattered plane reads. xsm layout + compute loop byte-identical to v3.
__global__ __launch_bounds__(256, 6) void conv_out_kernel(
    const float* __restrict__ x, const float* __restrict__ wt,
    const float* __restrict__ b, float* __restrict__ y)
{
  __shared__ __align__(16) float xsm[16 * 100 * 4];   // 25,600 B
  int tid = threadIdx.x;
  int bx = blockIdx.x & 15, by = blockIdx.x >> 4;
  int oy0 = by * 8, ox0 = bx * 8;

  for (int u = tid; u < 1600; u += 256) {
    int cq = u / 100;
    int pos = u - cq * 100;
    int row = pos / 10;
    int col = pos - row * 10;
    int gy = oy0 + row, gx = ox0 + col;
    float4 v = make_float4(0.f, 0.f, 0.f, 0.f);
    if (gy < IH && gx < IW)
      v = *(const float4*)&x[(gy * IW + gx) * 64 + cq * 4];
    *(float4*)&xsm[u * 4] = v;
  }
  __syncthreads();

  int ln = tid & 63;
  int px = ln & 7, py = ln >> 3;
  int wv_ = __builtin_amdgcn_readfirstlane(tid >> 6);   // wave 0..3
  int oc8 = blockIdx.y * 32 + wv_ * 8;

  float acc[8];
#pragma unroll
  for (int j = 0; j < 8; j++) acc[j] = b[oc8 + j];

#pragma unroll
  for (int ky = 0; ky < 3; ky++) {
#pragma unroll
    for (int kx = 0; kx < 3; kx++) {
      int k = ky * 3 + kx;
      int pidx = (py + ky) * 10 + px + kx;
      const float* wp = wt + k * 64 * 128 + oc8;   // uniform -> s_loads
#pragma unroll 4
      for (int cq = 0; cq < 16; cq++) {
        float4 xv = *(const float4*)&xsm[(cq * 100 + pidx) * 4];
        const float* wq = wp + cq * 4 * 128;
#pragma unroll
        for (int j = 0; j < 8; j++) {
          acc[j] = fmaf(xv.x, wq[0 * 128 + j], acc[j]);
          acc[j] = fmaf(xv.y, wq[1 * 128 + j], acc[j]);
          acc[j] = fmaf(xv.z, wq[2 * 128 + j], acc[j]);
          acc[j] = fmaf(xv.w, wq[3 * 128 + j], acc[j]);
        }
      }
    }
  }

  int oy = oy0 + py, ox = ox0 + px;
  if (oy < OH && ox < OW) {
#pragma unroll
    for (int j = 0; j < 8; j++)
      y[(oc8 + j) * OHW + oy * OW + ox] = acc[j];
  }
}

// ---------------------------------------------------------------- launch
extern "C" void kernel_launch(void* const* d_in, const int* in_sizes, int n_in,
                              void* d_out, int out_size, void* d_ws, size_t ws_size,
                              hipStream_t stream)
{
  const float* input = (const float*)d_in[0];
  const float* ciw   = (const float*)d_in[1];
  const float* cib   = (const float*)d_in[2];
  const float* wred  = (const float*)d_in[3];
  const float* bred  = (const float*)d_in[4];
  const float* gam   = (const float*)d_in[5];
  const float* bet   = (const float*)d_in[6];
  const float* mu    = (const float*)d_in[7];
  const float* var   = (const float*)d_in[8];
  const float* wspan = (const float*)d_in[9];
  const float* bspan = (const float*)d_in[10];
  const float* cow   = (const float*)d_in[11];
  const float* cob   = (const float*)d_in[12];
  float* out = (float*)d_out;

  float* bufA = (float*)d_ws;                 // HWC: 15876*64 = 1,016,064 floats
  float* bufB = bufA + (1 << 20);             // @ 4 MiB
  float* wt   = bufA + (1 << 21);             // @ 8 MiB, 73,728 floats

  transpose_w_kernel<<<288, 256, 0, stream>>>(cow, wt);
  conv_in_kernel<<<3969, 256, 0, stream>>>(input, ciw, cib, bufA);

  float* cur = bufA; float* nxt = bufB;
  for (int i = 0; i < 6; i++) {
    inv_kernel<<<512, 512, 0, stream>>>(cur, nxt,
        wred + i * 16 * 64, bred + i * 16, gam + i * 16, bet + i * 16,
        mu + i * 16, var + i * 16, wspan + i * 196 * 16, bspan + i * 196);
    float* t = cur; cur = nxt; nxt = t;
  }
  conv_out_kernel<<<dim3(256, 4), 256, 0, stream>>>(cur, wt, cob, out);
}